// Round 20
// baseline (121.833 us; speedup 1.0000x reference)
//
#include <hip/hip_runtime.h>

#define HEADS 4
#define DIM_HEAD 32
#define NB 2
#define NC 256
#define HW 4096
#define HIDDEN 128
#define NBH (NB*HEADS)

typedef _Float16 f16;
typedef _Float16 f16x8 __attribute__((ext_vector_type(8)));
typedef __fp16 fp16x2 __attribute__((ext_vector_type(2)));
typedef float f32x4 __attribute__((ext_vector_type(4)));

// workspace layout (bytes).  r20: XT/WQH/WOH DELETED -- prep is fully folded
// into its consumers (B-fragments converted from fp32 weights in-register;
// A staged through LDS into registers inside qkv).  3 kernels, 2 boundaries.
#define QT_OFF   (4u<<20)                 // f16 [bh][s][d32]     2 MB (rowstride 32 = coalesced)
#define KT_OFF   (6u<<20)                 // f16 [bh][s][d32]     2 MB
#define VH_OFF   (8u<<20)                 // f16 [bh][s/32][d32][32]  2 MB  (chunk-tiled, cols permuted)
#define HIDT_OFF (10u<<20)                // f16 [b][s/16][c/32=4][16][32]   2 MB (fragment-tiled)

#define QSCALE (0.17677669529663687f * 1.4426950408889634f)

__device__ __forceinline__ f16x8 ldg_f16x8(const f16* p) {
    union { uint4 u; f16x8 v; } t;
    t.u = *reinterpret_cast<const uint4*>(p);
    return t.v;
}
__device__ __forceinline__ unsigned packh2(float a, float b) {
    union { fp16x2 h; unsigned u; } t;
    t.h = __builtin_amdgcn_cvt_pkrtz(a, b);
    return t.u;
}

#define MFMA16(A,B,C) __builtin_amdgcn_mfma_f32_16x16x32_f16(A,B,C,0,0,0)

// ---------------------------------------------------------------------------
// qkv_mfma: C[s][o_lin] = X^T * Wqkv^T  (f16 MFMA, K=256), PREP-FREE (r20).
// A: per block, stage x[b][c0:256][s0:s0+64] through T[64][65] LDS transpose
//    (prep's exact pattern, 2-way bank aliasing = free) and convert with
//    packh2 straight into REGISTERS: 16 f16x8 = the wave's 16 A-fragments.
// B: fragments need 8 consecutive-c of wqkv[o_g][c] -- c-contiguous in the
//    raw fp32 weights, so load 2xfloat4 + packh2 (+QSCALE for Q rows)
//    in-register.  Bit-identical values to the old WQH (same rtz pairing).
// Epilogue unchanged: QT/KT s-major, VH chunk-tiled + col-permuted (r0/r11).
// NO launch_bounds min-occupancy arg (r2/r4: any hint -> spill storm).
// ---------------------------------------------------------------------------
__global__ __launch_bounds__(256) void qkv_mfma(const float* __restrict__ x,
                                                const float* __restrict__ wqkv,
                                                f16* __restrict__ qt,
                                                f16* __restrict__ kt,
                                                f16* __restrict__ vh) {
    __shared__ float T[64][65];
    const int w = threadIdx.x >> 6, lane = threadIdx.x & 63;
    const int q15 = lane & 15, quad = lane >> 4;
    const int b = blockIdx.z;
    const int s0g = blockIdx.x * 64;
    const int sTile = s0g + (w & 1) * 32;
    const int oTile = blockIdx.y * 64 + (w >> 1) * 32;

    // ---- stage A into registers: 4 c-chunks of 64 through LDS transpose ----
    f16x8 a[8][2];   // [k-chunk kt = c/32][s-half h]
    #pragma unroll
    for (int cc = 0; cc < 256; cc += 64) {
        if (cc) __syncthreads();                 // drain prev reads of T
        #pragma unroll
        for (int i = 0; i < 16; ++i) {
            int e = threadIdx.x + i * 256;
            int c = e >> 6, s = e & 63;
            T[c][s] = x[((size_t)(b * NC + cc + c)) * HW + s0g + s];
        }
        __syncthreads();
        #pragma unroll
        for (int ktl = 0; ktl < 2; ++ktl)
            #pragma unroll
            for (int h = 0; h < 2; ++h) {
                const int sl = (w & 1) * 32 + h * 16 + q15;
                const int cb = ktl * 32 + quad * 8;
                union { unsigned u[4]; f16x8 v; } t;
                #pragma unroll
                for (int j = 0; j < 4; ++j)
                    t.u[j] = packh2(T[cb + 2 * j][sl], T[cb + 2 * j + 1][sl]);
                a[(cc >> 5) + ktl][h] = t.v;
            }
    }

    // ---- B source rows (permuted) + wave-uniform scale ----
    const int o0 = oTile + q15, o1 = oTile + 16 + q15;
    const int wh0 = o0 >> 7, r0 = o0 & 127;
    const int og0 = (r0 >> 5) * 96 + (r0 & 31) * 3 + wh0;
    const int wh1 = o1 >> 7, r1 = o1 & 127;
    const int og1 = (r1 >> 5) * 96 + (r1 & 31) * 3 + wh1;
    const float scl0 = (wh0 == 0) ? QSCALE : 1.0f;
    const float scl1 = (wh1 == 0) ? QSCALE : 1.0f;
    const float* W0 = wqkv + og0 * 256 + quad * 8;
    const float* W1 = wqkv + og1 * 256 + quad * 8;

    f32x4 acc[2][2];
    #pragma unroll
    for (int i = 0; i < 2; ++i)
        #pragma unroll
        for (int j = 0; j < 2; ++j) acc[i][j] = (f32x4){0.f, 0.f, 0.f, 0.f};

    #pragma unroll
    for (int kt = 0; kt < 8; ++kt) {
        float4 p0 = *reinterpret_cast<const float4*>(W0 + kt * 32);
        float4 p1 = *reinterpret_cast<const float4*>(W0 + kt * 32 + 4);
        float4 r0v = *reinterpret_cast<const float4*>(W1 + kt * 32);
        float4 r1v = *reinterpret_cast<const float4*>(W1 + kt * 32 + 4);
        union { unsigned u[4]; f16x8 v; } b0, b1;
        b0.u[0] = packh2(p0.x * scl0, p0.y * scl0);
        b0.u[1] = packh2(p0.z * scl0, p0.w * scl0);
        b0.u[2] = packh2(p1.x * scl0, p1.y * scl0);
        b0.u[3] = packh2(p1.z * scl0, p1.w * scl0);
        b1.u[0] = packh2(r0v.x * scl1, r0v.y * scl1);
        b1.u[1] = packh2(r0v.z * scl1, r0v.w * scl1);
        b1.u[2] = packh2(r1v.x * scl1, r1v.y * scl1);
        b1.u[3] = packh2(r1v.z * scl1, r1v.w * scl1);
        acc[0][0] = MFMA16(a[kt][0], b0.v, acc[0][0]);
        acc[0][1] = MFMA16(a[kt][0], b1.v, acc[0][1]);
        acc[1][0] = MFMA16(a[kt][1], b0.v, acc[1][0]);
        acc[1][1] = MFMA16(a[kt][1], b1.v, acc[1][1]);
    }

    #pragma unroll
    for (int si = 0; si < 2; ++si)
        #pragma unroll
        for (int oj = 0; oj < 2; ++oj) {
            int o_lin = oTile + oj * 16 + q15;
            int which = o_lin >> 7;           // wave-uniform (tiles pure)
            int r = o_lin & 127;
            int head = r >> 5, d = r & 31;
            int bh = b * HEADS + head;
            int s2 = sTile + si * 16 + quad * 4;
            if (which == 2) {
                // keys s2..s2+3 (= si*16+quad*4+r2 within chunk sTile>>5) land
                // at within-chunk cols quad*8 + si*4 + r2 (permutation, r0)
                uint2 pv;
                pv.x = packh2(acc[si][oj][0], acc[si][oj][1]);
                pv.y = packh2(acc[si][oj][2], acc[si][oj][3]);
                f16* dst = vh + ((((size_t)bh * 128 + (sTile >> 5)) * 32 + d) << 5)
                              + quad * 8 + si * 4;
                *reinterpret_cast<uint2*>(dst) = pv;
            } else {
                f16* dst = (which == 0 ? qt : kt) + (size_t)bh * HW * 32;
                #pragma unroll
                for (int r2 = 0; r2 < 4; ++r2)
                    dst[(size_t)(s2 + r2) * 32 + d] = (f16)acc[si][oj][r2];
            }
        }
}

// ---------------------------------------------------------------------------
// attn_fused: MFMA flash attention WITH FUSED SPLIT REDUCTION (r14/r15 form,
// harness-verified; FROZEN -- r16 ones-MFMA, r17 setprio/rotation all null).
// One block = one 32-row q-tile; 4 waves split the key axis (w*1024 keys
// each, 16 double-chunk iters).  Post-loop: acc -> LDS (16KB), shfl
// row-sums -> LDS, one barrier, 256 threads reduce the 4 partials,
// normalize, write the 2KB HIDT tile directly.
// XCD-AFFINITY: block L -> XCD L&7 = bh; each XCD owns ONE bh entirely.
// Grid 1024 = 4 blocks/CU, one generation.
// NO launch_bounds min-occupancy arg (r2/r4: any hint -> spill storm).
// ---------------------------------------------------------------------------
#define LDKV(kd0,kd1,vd0,vd1,J)                                             \
    kd0 = ldg_f16x8(Kb + (size_t)((J) + q15) * 32 + quad * 8);              \
    kd1 = ldg_f16x8(Kb + (size_t)((J) + 16 + q15) * 32 + quad * 8);         \
    vd0 = ldg_f16x8(Vb + (((size_t)((J) >> 5) * 32 + q15) << 5) + quad * 8);\
    vd1 = ldg_f16x8(Vb + (((size_t)((J) >> 5) * 32 + 16 + q15) << 5) + quad * 8);

#define CHUNK(kf0_,kf1_,vf0_,vf1_)                                       \
    {                                                                    \
        const f32x4 z = {0.f, 0.f, 0.f, 0.f};                            \
        f32x4 s0a = MFMA16(kf0_, qf0, z);                                \
        f32x4 s1a = MFMA16(kf1_, qf0, z);                                \
        f32x4 s0b = MFMA16(kf0_, qf1, z);                                \
        f32x4 s1b = MFMA16(kf1_, qf1, z);                                \
        float ea[8], eb[8];                                              \
        _Pragma("unroll")                                                \
        for (int r = 0; r < 4; ++r) {                                    \
            ea[r]   = __builtin_amdgcn_exp2f(s0a[r]);                    \
            ea[4+r] = __builtin_amdgcn_exp2f(s1a[r]);                    \
            eb[r]   = __builtin_amdgcn_exp2f(s0b[r]);                    \
            eb[4+r] = __builtin_amdgcn_exp2f(s1b[r]);                    \
        }                                                                \
        l0 += (ea[0]+ea[1])+(ea[2]+ea[3])+(ea[4]+ea[5])+(ea[6]+ea[7]);   \
        l1 += (eb[0]+eb[1])+(eb[2]+eb[3])+(eb[4]+eb[5])+(eb[6]+eb[7]);   \
        union { unsigned u[4]; f16x8 v; } pa, pb;                        \
        pa.u[0] = packh2(ea[0], ea[1]); pa.u[1] = packh2(ea[2], ea[3]);  \
        pa.u[2] = packh2(ea[4], ea[5]); pa.u[3] = packh2(ea[6], ea[7]);  \
        pb.u[0] = packh2(eb[0], eb[1]); pb.u[1] = packh2(eb[2], eb[3]);  \
        pb.u[2] = packh2(eb[4], eb[5]); pb.u[3] = packh2(eb[6], eb[7]);  \
        acc[0][0] = MFMA16(vf0_, pa.v, acc[0][0]);                       \
        acc[0][1] = MFMA16(vf1_, pa.v, acc[0][1]);                       \
        acc[1][0] = MFMA16(vf0_, pb.v, acc[1][0]);                       \
        acc[1][1] = MFMA16(vf1_, pb.v, acc[1][1]);                       \
    }

__global__ __launch_bounds__(256) void attn_fused(const f16* __restrict__ qt,
                                                  const f16* __restrict__ kt,
                                                  const f16* __restrict__ vh,
                                                  f16* __restrict__ hidt) {
    __shared__ float Lo[4 * 4 * 256];   // [w][qb*2+t][lane*4+r]  16 KB
    __shared__ float Ll[4][2][16];      // [w][qb][q15] row-sums   512 B
    const int w    = threadIdx.x >> 6;
    const int lane = threadIdx.x & 63;
    const int q15  = lane & 15;
    const int quad = lane >> 4;

    const int L    = blockIdx.x;        // 0..1023
    const int bh   = L & 7;             // = XCD id (round-robin dispatch)
    const int qblk = L >> 3;            // 0..127
    const int qbase = qblk * 32;

    const f16* Qb = qt + (size_t)bh * HW * 32;
    const f16* Kb = kt + (size_t)bh * HW * 32;
    const f16* Vb = vh + (size_t)bh * 128 * 1024;   // [chunk][d][32] tiles

    f16x8 qf0 = ldg_f16x8(Qb + (size_t)(qbase + q15) * 32 + quad * 8);
    f16x8 qf1 = ldg_f16x8(Qb + (size_t)(qbase + 16 + q15) * 32 + quad * 8);

    f32x4 acc[2][2];
    #pragma unroll
    for (int a = 0; a < 2; ++a)
        #pragma unroll
        for (int b2 = 0; b2 < 2; ++b2)
            acc[a][b2] = (f32x4){0.f, 0.f, 0.f, 0.f};
    float l0 = 0.f, l1 = 0.f;

    const int j0   = w * 1024;                // wave = key-split
    const int span = min(1024, HW - j0);      // ==1024; opaque to unroller (r8)

    f16x8 ka0, ka1, va0, va1, kb0, kb1, vb0, vb1;
    LDKV(ka0, ka1, va0, va1, j0);
    LDKV(kb0, kb1, vb0, vb1, j0 + 32);

    for (int jc = 0; jc < span; jc += 64) {
        CHUNK(ka0, ka1, va0, va1);
        LDKV(ka0, ka1, va0, va1, j0 + jc + 64);   // last-iter prefetch reads
        CHUNK(kb0, kb1, vb0, vb1);                // past span: valid ws mem,
        LDKV(kb0, kb1, vb0, vb1, j0 + jc + 96);   // values unused
    }

    // per-wave row-sums: after two xors every lane holds its q-row's sum
    l0 += __shfl_xor(l0, 16, 64);
    l0 += __shfl_xor(l0, 32, 64);
    l1 += __shfl_xor(l1, 16, 64);
    l1 += __shfl_xor(l1, 32, 64);
    if (quad == 0) { Ll[w][0][q15] = l0; Ll[w][1][q15] = l1; }

    float* Wo = Lo + w * 1024;
    #pragma unroll
    for (int qb = 0; qb < 2; ++qb)
        #pragma unroll
        for (int t = 0; t < 2; ++t)
            *reinterpret_cast<f32x4*>(Wo + (qb * 2 + t) * 256 + lane * 4) = acc[qb][t];
    __syncthreads();

    // reduce 4 key-splits, normalize, write HIDT tile (2KB)
    const int row  = threadIdx.x >> 3;   // 0..31
    const int dg   = threadIdx.x & 7;    // 0..7
    const int qb   = row >> 4, q15r = row & 15;
    const int t_   = dg >> 2, quadr = dg & 3;
    const float l = Ll[0][qb][q15r] + Ll[1][qb][q15r] + Ll[2][qb][q15r] + Ll[3][qb][q15r];
    const float inv = 1.0f / l;
    float o0 = 0.f, o1 = 0.f, o2 = 0.f, o3 = 0.f;
    #pragma unroll
    for (int ww = 0; ww < 4; ++ww) {
        const float* p = Lo + ww * 1024 + (qb * 2 + t_) * 256 + (quadr * 16 + q15r) * 4;
        o0 += p[0]; o1 += p[1]; o2 += p[2]; o3 += p[3];
    }
    uint2 pv;
    pv.x = packh2(o0 * inv, o1 * inv);
    pv.y = packh2(o2 * inv, o3 * inv);
    const int s = qbase + row;
    const int b = bh >> 2, h = bh & 3;
    const int d = t_ * 16 + quadr * 4;
    f16* dst = hidt + ((((size_t)(b * 256 + (s >> 4))) * 4 + h) << 9)
                    + (s & 15) * 32 + d;
    *reinterpret_cast<uint2*>(dst) = pv;
}

// ---------------------------------------------------------------------------
// outp_mfma: out[b][o][s] = HIDT * Wout^T + bias  (f16 MFMA, K=128, fp32 out)
// A from HIDT (fragment-tiled, 1KB wave loads).  B converted in-register
// from fp32 wout (c-contiguous: 2xfloat4 + packh2 per fragment) -- r20,
// deletes WOH and the prep kernel.
// ---------------------------------------------------------------------------
__global__ __launch_bounds__(256) void outp_mfma(const f16* __restrict__ hidt,
                                                 const float* __restrict__ wout,
                                                 const float* __restrict__ bout,
                                                 float* __restrict__ out) {
    const int w = threadIdx.x >> 6, lane = threadIdx.x & 63;
    const int q15 = lane & 15, quad = lane >> 4;
    const int b = blockIdx.z;
    const int sTile = blockIdx.x * 64 + (w & 1) * 32;
    const int oTile = blockIdx.y * 64 + (w >> 1) * 32;
    const f16* At = hidt + (((size_t)(b * 256 + (sTile >> 4))) << 11);  // *4 tiles *512
    const int fo = q15 * 32 + quad * 8;
    const float* W0 = wout + (oTile + q15) * 128 + quad * 8;
    const float* W1 = wout + (oTile + 16 + q15) * 128 + quad * 8;

    f32x4 acc[2][2];
    #pragma unroll
    for (int i = 0; i < 2; ++i)
        #pragma unroll
        for (int j = 0; j < 2; ++j) acc[i][j] = (f32x4){0.f, 0.f, 0.f, 0.f};

    #pragma unroll
    for (int kt = 0; kt < 4; ++kt) {
        f16x8 a0 = ldg_f16x8(At + kt * 512 + fo);
        f16x8 a1 = ldg_f16x8(At + 2048 + kt * 512 + fo);
        float4 p0 = *reinterpret_cast<const float4*>(W0 + kt * 32);
        float4 p1 = *reinterpret_cast<const float4*>(W0 + kt * 32 + 4);
        float4 r0v = *reinterpret_cast<const float4*>(W1 + kt * 32);
        float4 r1v = *reinterpret_cast<const float4*>(W1 + kt * 32 + 4);
        union { unsigned u[4]; f16x8 v; } b0, b1;
        b0.u[0] = packh2(p0.x, p0.y);  b0.u[1] = packh2(p0.z, p0.w);
        b0.u[2] = packh2(p1.x, p1.y);  b0.u[3] = packh2(p1.z, p1.w);
        b1.u[0] = packh2(r0v.x, r0v.y); b1.u[1] = packh2(r0v.z, r0v.w);
        b1.u[2] = packh2(r1v.x, r1v.y); b1.u[3] = packh2(r1v.z, r1v.w);
        acc[0][0] = MFMA16(a0, b0.v, acc[0][0]);
        acc[0][1] = MFMA16(a0, b1.v, acc[0][1]);
        acc[1][0] = MFMA16(a1, b0.v, acc[1][0]);
        acc[1][1] = MFMA16(a1, b1.v, acc[1][1]);
    }

    #pragma unroll
    for (int oj = 0; oj < 2; ++oj) {
        const int o = oTile + oj * 16 + q15;
        const float bias = bout[o];
        #pragma unroll
        for (int si = 0; si < 2; ++si) {
            const int s2 = sTile + si * 16 + quad * 4;
            float4 v = make_float4(acc[si][oj][0] + bias, acc[si][oj][1] + bias,
                                   acc[si][oj][2] + bias, acc[si][oj][3] + bias);
            *reinterpret_cast<float4*>(out + ((size_t)(b * NC + o)) * HW + s2) = v;
        }
    }
}

// ---------------------------------------------------------------------------
extern "C" void kernel_launch(void* const* d_in, const int* in_sizes, int n_in,
                              void* d_out, int out_size, void* d_ws, size_t ws_size,
                              hipStream_t stream) {
    const float* x    = (const float*)d_in[0];
    const float* wqkv = (const float*)d_in[1];
    const float* wout = (const float*)d_in[2];
    const float* bout = (const float*)d_in[3];
    float* out = (float*)d_out;
    char* wsb  = (char*)d_ws;

    f16*   QT   = (f16*)(wsb + QT_OFF);
    f16*   KT   = (f16*)(wsb + KT_OFF);
    f16*   VH   = (f16*)(wsb + VH_OFF);
    f16*   HIDT = (f16*)(wsb + HIDT_OFF);

    qkv_mfma  <<<dim3(64, 6, NB), 256, 0, stream>>>(x, wqkv, QT, KT, VH);
    attn_fused<<<dim3(1024), 256, 0, stream>>>(QT, KT, VH, HIDT);
    outp_mfma <<<dim3(64, 4, NB), 256, 0, stream>>>(HIDT, wout, bout, out);
}

// Round 21
// 113.227 us; speedup vs baseline: 1.0760x; 1.0760x over previous
//
#include <hip/hip_runtime.h>

#define HEADS 4
#define DIM_HEAD 32
#define NB 2
#define NC 256
#define HW 4096
#define HIDDEN 128
#define NBH (NB*HEADS)
#define ROWS_TOTAL (NBH*HW)   // 32768

typedef _Float16 f16;
typedef _Float16 f16x8 __attribute__((ext_vector_type(8)));
typedef __fp16 fp16x2 __attribute__((ext_vector_type(2)));
typedef float f32x4 __attribute__((ext_vector_type(4)));

// workspace layout (bytes).  ALL mfma operand arrays are FRAGMENT-TILED:
// [row/16][k/32][16][32] f16 (1KB tiles) so every A/B fragment load
// (base + q15*32 + quad*8) is ONE contiguous 1KB wave access (r11/r12).
#define XT_OFF   0u                       // f16 [b][s/16][c/32=8][16][32]   4 MB
#define QT_OFF   (4u<<20)                 // f16 [bh][s][d32]     2 MB (rowstride 32 = coalesced)
#define KT_OFF   (6u<<20)                 // f16 [bh][s][d32]     2 MB
#define VH_OFF   (8u<<20)                 // f16 [bh][s/32][d32][32]  2 MB  (chunk-tiled, cols permuted)
#define HIDT_OFF (10u<<20)                // f16 [b][s/16][c/32=4][16][32]   2 MB
#define WQH_OFF  (12u<<20)                // f16 [384/16][256/32=8][16][32]  192 KB
#define WOH_OFF  ((12u<<20) + (256u<<10)) // f16 [256/16][128/32=4][16][32]  64 KB
// PART deleted (r14: split reduction fused into attn via LDS)
// r18: cooperative mega-fusion fails in this harness (graph capture +
//      cross-XCD coherence); r20: folding prep into qkv regresses (+7.8us:
//      6x x re-read, per-block weight conversion, staging barriers).
//      The 4-launch pipeline below is the verified optimum of this session.

__device__ __forceinline__ f16x8 ldg_f16x8(const f16* p) {
    union { uint4 u; f16x8 v; } t;
    t.u = *reinterpret_cast<const uint4*>(p);
    return t.v;
}
__device__ __forceinline__ unsigned packh2(float a, float b) {
    union { fp16x2 h; unsigned u; } t;
    t.h = __builtin_amdgcn_cvt_pkrtz(a, b);
    return t.u;
}

// ---------------------------------------------------------------------------
// prep: FUSED wconv + xpose (independent preprocessing, block-partitioned).
// blocks 0..511: xpose  x[b][c][s] fp32 -> XT tiled [b][s/16][c/32][16][32]
// blocks 512..639: wconv -> WQH/WOH tiled
// ---------------------------------------------------------------------------
__global__ __launch_bounds__(256) void prep(const float* __restrict__ x,
                                            const float* __restrict__ wqkv,
                                            const float* __restrict__ wout,
                                            f16* __restrict__ xt,
                                            f16* __restrict__ wqh,
                                            f16* __restrict__ woh) {
    __shared__ float T[64][65];
    if (blockIdx.x < 512) {
        const int idx = blockIdx.x;
        const int b = idx >> 8, rem = idx & 255;
        const int c0 = (rem >> 6) * 64, s0 = (rem & 63) * 64;
        const int t = threadIdx.x;
        #pragma unroll
        for (int i = 0; i < 16; ++i) {
            int e = t + i * 256;
            int c = e >> 6, s = e & 63;
            T[c][s] = x[((size_t)(b * NC + c0 + c)) * HW + s0 + s];
        }
        __syncthreads();
        const int s = t >> 2, cg = (t & 3) * 16;
        unsigned ov[8];
        #pragma unroll
        for (int i = 0; i < 8; ++i)
            ov[i] = packh2(T[cg + 2 * i][s], T[cg + 2 * i + 1][s]);
        const int srow = s0 + s;
        f16* dst = xt + ((((size_t)(b * 256 + (srow >> 4))) * 8 + ((c0 + cg) >> 5)) << 9)
                      + (srow & 15) * 32 + (cg & 31);
        *reinterpret_cast<uint4*>(dst)     = make_uint4(ov[0], ov[1], ov[2], ov[3]);
        *reinterpret_cast<uint4*>(dst + 8) = make_uint4(ov[4], ov[5], ov[6], ov[7]);
        return;
    }
    const int tid = (blockIdx.x - 512) * 256 + threadIdx.x;
    const float QSCALE = 0.17677669529663687f * 1.4426950408889634f;
    if (tid < 24576) {                       // 384*256/4
        int o_lin = tid >> 6;
        int c4 = (tid & 63) * 4;
        int which = o_lin >> 7, r = o_lin & 127;
        int head = r >> 5, d = r & 31;
        int o_g = head * 96 + d * 3 + which;
        float4 v = *reinterpret_cast<const float4*>(wqkv + o_g * 256 + c4);
        float scl = (which == 0) ? QSCALE : 1.0f;
        uint2 pv;
        pv.x = packh2(v.x * scl, v.y * scl);
        pv.y = packh2(v.z * scl, v.w * scl);
        f16* dst = wqh + (((o_lin >> 4) * 8 + (c4 >> 5)) << 9)
                       + (o_lin & 15) * 32 + (c4 & 31);
        *reinterpret_cast<uint2*>(dst) = pv;
    } else if (tid < 24576 + 8192) {         // 256*128/4
        int t2 = tid - 24576;
        int o = t2 >> 5;                     // row in [0,256)
        int c4 = (t2 * 4) & 127;             // col in [0,128)
        float4 v = *reinterpret_cast<const float4*>(wout + t2 * 4);
        uint2 pv;
        pv.x = packh2(v.x, v.y);
        pv.y = packh2(v.z, v.w);
        f16* dst = woh + (((o >> 4) * 4 + (c4 >> 5)) << 9)
                       + (o & 15) * 32 + (c4 & 31);
        *reinterpret_cast<uint2*>(dst) = pv;
    }
}

// ---------------------------------------------------------------------------
// qkv_mfma: C[s][o_lin] = XT * WQH^T  (f16 MFMA, K=256).  XT/WQH tiled ->
// every fragment load is one contiguous 1KB wave access.  K-loop A/B
// double-buffered (r15).  Last-iter prefetch reads <=10KB past XT/WQH into
// adjacent ws (valid, unused).  VH chunk-tiled, cols permuted (r0/r11).
// ---------------------------------------------------------------------------
__global__ __launch_bounds__(256) void qkv_mfma(const f16* __restrict__ xt,
                                                const f16* __restrict__ wqh,
                                                f16* __restrict__ qt,
                                                f16* __restrict__ kt,
                                                f16* __restrict__ vh) {
    const int w = threadIdx.x >> 6, lane = threadIdx.x & 63;
    const int q15 = lane & 15, quad = lane >> 4;
    const int b = blockIdx.z;
    const int sTile = blockIdx.x * 64 + (w & 1) * 32;
    const int oTile = blockIdx.y * 64 + (w >> 1) * 32;
    const f16* At = xt + (((size_t)(b * 256 + (sTile >> 4))) << 12);  // *8 tiles *512
    const f16* Bt = wqh + (((size_t)(oTile >> 4)) << 12);
    const int fo = q15 * 32 + quad * 8;

    f32x4 acc[2][2];
    #pragma unroll
    for (int i = 0; i < 2; ++i)
        #pragma unroll
        for (int j = 0; j < 2; ++j) acc[i][j] = (f32x4){0.f, 0.f, 0.f, 0.f};

    f16x8 xa0 = ldg_f16x8(At + fo);
    f16x8 xa1 = ldg_f16x8(At + 4096 + fo);
    f16x8 xb0 = ldg_f16x8(Bt + fo);
    f16x8 xb1 = ldg_f16x8(Bt + 4096 + fo);
    f16x8 ya0 = ldg_f16x8(At + 512 + fo);
    f16x8 ya1 = ldg_f16x8(At + 4096 + 512 + fo);
    f16x8 yb0 = ldg_f16x8(Bt + 512 + fo);
    f16x8 yb1 = ldg_f16x8(Bt + 4096 + 512 + fo);

    #pragma unroll
    for (int kc = 0; kc < 256; kc += 64) {
        const int nx = (kc + 64) * 16;   // f16 offset of k-tile (kc+64)/32
        const int ny = (kc + 96) * 16;
        acc[0][0] = __builtin_amdgcn_mfma_f32_16x16x32_f16(xa0, xb0, acc[0][0], 0, 0, 0);
        acc[0][1] = __builtin_amdgcn_mfma_f32_16x16x32_f16(xa0, xb1, acc[0][1], 0, 0, 0);
        acc[1][0] = __builtin_amdgcn_mfma_f32_16x16x32_f16(xa1, xb0, acc[1][0], 0, 0, 0);
        acc[1][1] = __builtin_amdgcn_mfma_f32_16x16x32_f16(xa1, xb1, acc[1][1], 0, 0, 0);
        xa0 = ldg_f16x8(At + nx + fo);            // last-iter prefetch lands in
        xa1 = ldg_f16x8(At + 4096 + nx + fo);     // adjacent ws region (valid,
        xb0 = ldg_f16x8(Bt + nx + fo);            // unused)
        xb1 = ldg_f16x8(Bt + 4096 + nx + fo);
        acc[0][0] = __builtin_amdgcn_mfma_f32_16x16x32_f16(ya0, yb0, acc[0][0], 0, 0, 0);
        acc[0][1] = __builtin_amdgcn_mfma_f32_16x16x32_f16(ya0, yb1, acc[0][1], 0, 0, 0);
        acc[1][0] = __builtin_amdgcn_mfma_f32_16x16x32_f16(ya1, yb0, acc[1][0], 0, 0, 0);
        acc[1][1] = __builtin_amdgcn_mfma_f32_16x16x32_f16(ya1, yb1, acc[1][1], 0, 0, 0);
        ya0 = ldg_f16x8(At + ny + fo);
        ya1 = ldg_f16x8(At + 4096 + ny + fo);
        yb0 = ldg_f16x8(Bt + ny + fo);
        yb1 = ldg_f16x8(Bt + 4096 + ny + fo);
    }

    #pragma unroll
    for (int si = 0; si < 2; ++si)
        #pragma unroll
        for (int oj = 0; oj < 2; ++oj) {
            int o_lin = oTile + oj * 16 + q15;
            int which = o_lin >> 7;           // wave-uniform (tiles pure)
            int r = o_lin & 127;
            int head = r >> 5, d = r & 31;
            int bh = b * HEADS + head;
            int s2 = sTile + si * 16 + quad * 4;
            if (which == 2) {
                // keys s2..s2+3 (= si*16+quad*4+r2 within chunk sTile>>5) land
                // at within-chunk cols quad*8 + si*4 + r2 (permutation, r0)
                uint2 pv;
                pv.x = packh2(acc[si][oj][0], acc[si][oj][1]);
                pv.y = packh2(acc[si][oj][2], acc[si][oj][3]);
                f16* dst = vh + ((((size_t)bh * 128 + (sTile >> 5)) * 32 + d) << 5)
                              + quad * 8 + si * 4;
                *reinterpret_cast<uint2*>(dst) = pv;
            } else {
                f16* dst = (which == 0 ? qt : kt) + (size_t)bh * HW * 32;
                #pragma unroll
                for (int r2 = 0; r2 < 4; ++r2)
                    dst[(size_t)(s2 + r2) * 32 + d] = (f16)acc[si][oj][r2];
            }
        }
}

// ---------------------------------------------------------------------------
// attn_fused: MFMA flash attention WITH FUSED SPLIT REDUCTION (r14/r15 form,
// harness-verified 113.19us total; FROZEN -- r16 ones-MFMA and r17
// setprio/rotation probes were null).  One block = one 32-row q-tile; 4
// waves split the key axis (w*1024 keys each, 16 double-chunk iters,
// r10/r11 inner loop).  Post-loop: acc -> LDS (16KB), shfl row-sums -> LDS,
// one barrier, 256 threads reduce the 4 partials, normalize, write the 2KB
// HIDT tile directly.
// XCD-AFFINITY: block L -> XCD L&7 = bh; each XCD owns ONE bh entirely.
// Grid 1024 = 4 blocks/CU, one generation.
// NO launch_bounds min-occupancy arg (r2/r4: any hint -> spill storm).
// ---------------------------------------------------------------------------
#define MFMA16(A,B,C) __builtin_amdgcn_mfma_f32_16x16x32_f16(A,B,C,0,0,0)

#define LDKV(kd0,kd1,vd0,vd1,J)                                             \
    kd0 = ldg_f16x8(Kb + (size_t)((J) + q15) * 32 + quad * 8);              \
    kd1 = ldg_f16x8(Kb + (size_t)((J) + 16 + q15) * 32 + quad * 8);         \
    vd0 = ldg_f16x8(Vb + (((size_t)((J) >> 5) * 32 + q15) << 5) + quad * 8);\
    vd1 = ldg_f16x8(Vb + (((size_t)((J) >> 5) * 32 + 16 + q15) << 5) + quad * 8);

#define CHUNK(kf0_,kf1_,vf0_,vf1_)                                       \
    {                                                                    \
        const f32x4 z = {0.f, 0.f, 0.f, 0.f};                            \
        f32x4 s0a = MFMA16(kf0_, qf0, z);                                \
        f32x4 s1a = MFMA16(kf1_, qf0, z);                                \
        f32x4 s0b = MFMA16(kf0_, qf1, z);                                \
        f32x4 s1b = MFMA16(kf1_, qf1, z);                                \
        float ea[8], eb[8];                                              \
        _Pragma("unroll")                                                \
        for (int r = 0; r < 4; ++r) {                                    \
            ea[r]   = __builtin_amdgcn_exp2f(s0a[r]);                    \
            ea[4+r] = __builtin_amdgcn_exp2f(s1a[r]);                    \
            eb[r]   = __builtin_amdgcn_exp2f(s0b[r]);                    \
            eb[4+r] = __builtin_amdgcn_exp2f(s1b[r]);                    \
        }                                                                \
        l0 += (ea[0]+ea[1])+(ea[2]+ea[3])+(ea[4]+ea[5])+(ea[6]+ea[7]);   \
        l1 += (eb[0]+eb[1])+(eb[2]+eb[3])+(eb[4]+eb[5])+(eb[6]+eb[7]);   \
        union { unsigned u[4]; f16x8 v; } pa, pb;                        \
        pa.u[0] = packh2(ea[0], ea[1]); pa.u[1] = packh2(ea[2], ea[3]);  \
        pa.u[2] = packh2(ea[4], ea[5]); pa.u[3] = packh2(ea[6], ea[7]);  \
        pb.u[0] = packh2(eb[0], eb[1]); pb.u[1] = packh2(eb[2], eb[3]);  \
        pb.u[2] = packh2(eb[4], eb[5]); pb.u[3] = packh2(eb[6], eb[7]);  \
        acc[0][0] = MFMA16(vf0_, pa.v, acc[0][0]);                       \
        acc[0][1] = MFMA16(vf1_, pa.v, acc[0][1]);                       \
        acc[1][0] = MFMA16(vf0_, pb.v, acc[1][0]);                       \
        acc[1][1] = MFMA16(vf1_, pb.v, acc[1][1]);                       \
    }

__global__ __launch_bounds__(256) void attn_fused(const f16* __restrict__ qt,
                                                  const f16* __restrict__ kt,
                                                  const f16* __restrict__ vh,
                                                  f16* __restrict__ hidt) {
    __shared__ float Lo[4 * 4 * 256];   // [w][qb*2+t][lane*4+r]  16 KB
    __shared__ float Ll[4][2][16];      // [w][qb][q15] row-sums   512 B
    const int w    = threadIdx.x >> 6;
    const int lane = threadIdx.x & 63;
    const int q15  = lane & 15;
    const int quad = lane >> 4;

    const int L    = blockIdx.x;        // 0..1023
    const int bh   = L & 7;             // = XCD id (round-robin dispatch)
    const int qblk = L >> 3;            // 0..127
    const int qbase = qblk * 32;

    const f16* Qb = qt + (size_t)bh * HW * 32;
    const f16* Kb = kt + (size_t)bh * HW * 32;
    const f16* Vb = vh + (size_t)bh * 128 * 1024;   // [chunk][d][32] tiles

    f16x8 qf0 = ldg_f16x8(Qb + (size_t)(qbase + q15) * 32 + quad * 8);
    f16x8 qf1 = ldg_f16x8(Qb + (size_t)(qbase + 16 + q15) * 32 + quad * 8);

    f32x4 acc[2][2];
    #pragma unroll
    for (int a = 0; a < 2; ++a)
        #pragma unroll
        for (int b2 = 0; b2 < 2; ++b2)
            acc[a][b2] = (f32x4){0.f, 0.f, 0.f, 0.f};
    float l0 = 0.f, l1 = 0.f;

    const int j0   = w * 1024;                // wave = key-split
    const int span = min(1024, HW - j0);      // ==1024; opaque to unroller (r8)

    f16x8 ka0, ka1, va0, va1, kb0, kb1, vb0, vb1;
    LDKV(ka0, ka1, va0, va1, j0);
    LDKV(kb0, kb1, vb0, vb1, j0 + 32);

    for (int jc = 0; jc < span; jc += 64) {
        CHUNK(ka0, ka1, va0, va1);
        LDKV(ka0, ka1, va0, va1, j0 + jc + 64);   // last-iter prefetch reads
        CHUNK(kb0, kb1, vb0, vb1);                // past span: valid ws mem,
        LDKV(kb0, kb1, vb0, vb1, j0 + jc + 96);   // values unused
    }

    // per-wave row-sums: after two xors every lane holds its q-row's sum
    l0 += __shfl_xor(l0, 16, 64);
    l0 += __shfl_xor(l0, 32, 64);
    l1 += __shfl_xor(l1, 16, 64);
    l1 += __shfl_xor(l1, 32, 64);
    if (quad == 0) { Ll[w][0][q15] = l0; Ll[w][1][q15] = l1; }

    float* Wo = Lo + w * 1024;
    #pragma unroll
    for (int qb = 0; qb < 2; ++qb)
        #pragma unroll
        for (int t = 0; t < 2; ++t)
            *reinterpret_cast<f32x4*>(Wo + (qb * 2 + t) * 256 + lane * 4) = acc[qb][t];
    __syncthreads();

    // reduce 4 key-splits, normalize, write HIDT tile (2KB)
    const int row  = threadIdx.x >> 3;   // 0..31
    const int dg   = threadIdx.x & 7;    // 0..7
    const int qb   = row >> 4, q15r = row & 15;
    const int t_   = dg >> 2, quadr = dg & 3;
    const float l = Ll[0][qb][q15r] + Ll[1][qb][q15r] + Ll[2][qb][q15r] + Ll[3][qb][q15r];
    const float inv = 1.0f / l;
    float o0 = 0.f, o1 = 0.f, o2 = 0.f, o3 = 0.f;
    #pragma unroll
    for (int ww = 0; ww < 4; ++ww) {
        const float* p = Lo + ww * 1024 + (qb * 2 + t_) * 256 + (quadr * 16 + q15r) * 4;
        o0 += p[0]; o1 += p[1]; o2 += p[2]; o3 += p[3];
    }
    uint2 pv;
    pv.x = packh2(o0 * inv, o1 * inv);
    pv.y = packh2(o2 * inv, o3 * inv);
    const int s = qbase + row;
    const int b = bh >> 2, h = bh & 3;
    const int d = t_ * 16 + quadr * 4;
    f16* dst = hidt + ((((size_t)(b * 256 + (s >> 4))) * 4 + h) << 9)
                    + (s & 15) * 32 + d;
    *reinterpret_cast<uint2*>(dst) = pv;
}

// ---------------------------------------------------------------------------
// outp_mfma: out[b][o][s] = HIDT * WOH^T + bias  (f16 MFMA, K=128, fp32 out)
// HIDT/WOH tiled -> fragment loads are contiguous 1KB wave accesses.
// K-loop A/B double-buffered (r15).  Last-iter prefetch reads <=6KB past
// HIDT/WOH into adjacent ws (valid, unused).
// ---------------------------------------------------------------------------
__global__ __launch_bounds__(256) void outp_mfma(const f16* __restrict__ hidt,
                                                 const f16* __restrict__ woh,
                                                 const float* __restrict__ bout,
                                                 float* __restrict__ out) {
    const int w = threadIdx.x >> 6, lane = threadIdx.x & 63;
    const int q15 = lane & 15, quad = lane >> 4;
    const int b = blockIdx.z;
    const int sTile = blockIdx.x * 64 + (w & 1) * 32;
    const int oTile = blockIdx.y * 64 + (w >> 1) * 32;
    const f16* At = hidt + (((size_t)(b * 256 + (sTile >> 4))) << 11);  // *4 tiles *512
    const f16* Bt = woh + (((size_t)(oTile >> 4)) << 11);
    const int fo = q15 * 32 + quad * 8;

    f32x4 acc[2][2];
    #pragma unroll
    for (int i = 0; i < 2; ++i)
        #pragma unroll
        for (int j = 0; j < 2; ++j) acc[i][j] = (f32x4){0.f, 0.f, 0.f, 0.f};

    f16x8 xa0 = ldg_f16x8(At + fo);
    f16x8 xa1 = ldg_f16x8(At + 2048 + fo);
    f16x8 xb0 = ldg_f16x8(Bt + fo);
    f16x8 xb1 = ldg_f16x8(Bt + 2048 + fo);
    f16x8 ya0 = ldg_f16x8(At + 512 + fo);
    f16x8 ya1 = ldg_f16x8(At + 2048 + 512 + fo);
    f16x8 yb0 = ldg_f16x8(Bt + 512 + fo);
    f16x8 yb1 = ldg_f16x8(Bt + 2048 + 512 + fo);

    #pragma unroll
    for (int kc = 0; kc < 128; kc += 64) {
        const int nx = (kc + 64) * 16;
        const int ny = (kc + 96) * 16;
        acc[0][0] = __builtin_amdgcn_mfma_f32_16x16x32_f16(xa0, xb0, acc[0][0], 0, 0, 0);
        acc[0][1] = __builtin_amdgcn_mfma_f32_16x16x32_f16(xa0, xb1, acc[0][1], 0, 0, 0);
        acc[1][0] = __builtin_amdgcn_mfma_f32_16x16x32_f16(xa1, xb0, acc[1][0], 0, 0, 0);
        acc[1][1] = __builtin_amdgcn_mfma_f32_16x16x32_f16(xa1, xb1, acc[1][1], 0, 0, 0);
        xa0 = ldg_f16x8(At + nx + fo);            // last-iter prefetch lands in
        xa1 = ldg_f16x8(At + 2048 + nx + fo);     // adjacent ws region (valid,
        xb0 = ldg_f16x8(Bt + nx + fo);            // unused)
        xb1 = ldg_f16x8(Bt + 2048 + nx + fo);
        acc[0][0] = __builtin_amdgcn_mfma_f32_16x16x32_f16(ya0, yb0, acc[0][0], 0, 0, 0);
        acc[0][1] = __builtin_amdgcn_mfma_f32_16x16x32_f16(ya0, yb1, acc[0][1], 0, 0, 0);
        acc[1][0] = __builtin_amdgcn_mfma_f32_16x16x32_f16(ya1, yb0, acc[1][0], 0, 0, 0);
        acc[1][1] = __builtin_amdgcn_mfma_f32_16x16x32_f16(ya1, yb1, acc[1][1], 0, 0, 0);
        ya0 = ldg_f16x8(At + ny + fo);
        ya1 = ldg_f16x8(At + 2048 + ny + fo);
        yb0 = ldg_f16x8(Bt + ny + fo);
        yb1 = ldg_f16x8(Bt + 2048 + ny + fo);
    }

    #pragma unroll
    for (int oj = 0; oj < 2; ++oj) {
        const int o = oTile + oj * 16 + q15;
        const float bias = bout[o];
        #pragma unroll
        for (int si = 0; si < 2; ++si) {
            const int s2 = sTile + si * 16 + quad * 4;
            float4 v = make_float4(acc[si][oj][0] + bias, acc[si][oj][1] + bias,
                                   acc[si][oj][2] + bias, acc[si][oj][3] + bias);
            *reinterpret_cast<float4*>(out + ((size_t)(b * NC + o)) * HW + s2) = v;
        }
    }
}

// ---------------------------------------------------------------------------
extern "C" void kernel_launch(void* const* d_in, const int* in_sizes, int n_in,
                              void* d_out, int out_size, void* d_ws, size_t ws_size,
                              hipStream_t stream) {
    const float* x    = (const float*)d_in[0];
    const float* wqkv = (const float*)d_in[1];
    const float* wout = (const float*)d_in[2];
    const float* bout = (const float*)d_in[3];
    float* out = (float*)d_out;
    char* wsb  = (char*)d_ws;

    f16*   XT   = (f16*)(wsb + XT_OFF);
    f16*   QT   = (f16*)(wsb + QT_OFF);
    f16*   KT   = (f16*)(wsb + KT_OFF);
    f16*   VH   = (f16*)(wsb + VH_OFF);
    f16*   HIDT = (f16*)(wsb + HIDT_OFF);
    f16*   WQH  = (f16*)(wsb + WQH_OFF);
    f16*   WOH  = (f16*)(wsb + WOH_OFF);

    prep      <<<dim3(640), 256, 0, stream>>>(x, wqkv, wout, XT, WQH, WOH);
    qkv_mfma  <<<dim3(64, 6, NB), 256, 0, stream>>>(XT, WQH, QT, KT, VH);
    attn_fused<<<dim3(1024), 256, 0, stream>>>(QT, KT, VH, HIDT);
    outp_mfma <<<dim3(64, 4, NB), 256, 0, stream>>>(HIDT, WOH, bout, out);
}